// Round 1
// baseline (5290.113 us; speedup 1.0000x reference)
//
#include <hip/hip_runtime.h>
#include <cmath>

// ---- problem constants ----
constexpr int D     = 1024;
constexpr int HEADS = 16;
constexpr int DH    = 64;
constexpr int HID   = 4096;
constexpr int NL    = 12;
constexpr int NC    = 256;
constexpr int CSZ   = 128;
constexpr int AGE_V = 258;
constexpr int OBS   = 2048;
constexpr int OUTN  = 512;
constexpr int S     = 257;   // 1 + NC
constexpr int SP    = 288;   // padded rows: 9 * 32, pad rows never read as outputs

// ---- fp32 NT GEMM: C[M,N] = A[M,K] @ B[N,K]^T + bias (+R) (+relu) ----
constexpr int BM = 32, BN = 64, BK = 32;

struct QKVArgs {
    const float* B[3];
    const float* bias[3];
    float* C[3];
};

template<bool RES, int ACT>
__device__ __forceinline__ void gemm_tile(const float* __restrict__ A,
                                          const float* __restrict__ B,
                                          const float* __restrict__ bias,
                                          const float* __restrict__ Rres,
                                          float* __restrict__ C,
                                          int K, int N) {
    // As transposed [k][m] (+2 pad keeps float2 8B-aligned), Bs [k][n] (+4 keeps float4 16B-aligned)
    __shared__ __align__(16) float As[BK][BM + 2];
    __shared__ __align__(16) float Bs[BK][BN + 4];
    const int t  = threadIdx.x;
    const int m0 = blockIdx.y * BM;
    const int n0 = blockIdx.x * BN;
    const int tx = t & 15;    // n-group: 4 cols each
    const int ty = t >> 4;    // m-group: 2 rows each
    const int m_a = t >> 3;          // 0..31
    const int ka  = (t & 7) << 2;    // 0,4,...,28
    const int n_b = t >> 2;          // 0..63
    const int kb  = (t & 3) << 3;    // 0,8,16,24
    const float* Aptr = A + (size_t)(m0 + m_a) * K + ka;
    const float* Bptr = B + (size_t)(n0 + n_b) * K + kb;
    float acc[2][4] = {};
    for (int k0 = 0; k0 < K; k0 += BK) {
        const float4 av  = *(const float4*)(Aptr + k0);
        const float4 bv0 = *(const float4*)(Bptr + k0);
        const float4 bv1 = *(const float4*)(Bptr + k0 + 4);
        __syncthreads();
        As[ka + 0][m_a] = av.x;
        As[ka + 1][m_a] = av.y;
        As[ka + 2][m_a] = av.z;
        As[ka + 3][m_a] = av.w;
        Bs[kb + 0][n_b] = bv0.x;
        Bs[kb + 1][n_b] = bv0.y;
        Bs[kb + 2][n_b] = bv0.z;
        Bs[kb + 3][n_b] = bv0.w;
        Bs[kb + 4][n_b] = bv1.x;
        Bs[kb + 5][n_b] = bv1.y;
        Bs[kb + 6][n_b] = bv1.z;
        Bs[kb + 7][n_b] = bv1.w;
        __syncthreads();
        #pragma unroll
        for (int kk = 0; kk < BK; ++kk) {
            const float2 a = *(const float2*)&As[kk][ty * 2];
            const float4 b = *(const float4*)&Bs[kk][tx * 4];
            acc[0][0] = fmaf(a.x, b.x, acc[0][0]);
            acc[0][1] = fmaf(a.x, b.y, acc[0][1]);
            acc[0][2] = fmaf(a.x, b.z, acc[0][2]);
            acc[0][3] = fmaf(a.x, b.w, acc[0][3]);
            acc[1][0] = fmaf(a.y, b.x, acc[1][0]);
            acc[1][1] = fmaf(a.y, b.y, acc[1][1]);
            acc[1][2] = fmaf(a.y, b.z, acc[1][2]);
            acc[1][3] = fmaf(a.y, b.w, acc[1][3]);
        }
    }
    const float4 b4 = *(const float4*)&bias[n0 + tx * 4];
    #pragma unroll
    for (int r = 0; r < 2; ++r) {
        const int m = m0 + ty * 2 + r;
        float4 v;
        v.x = acc[r][0] + b4.x;
        v.y = acc[r][1] + b4.y;
        v.z = acc[r][2] + b4.z;
        v.w = acc[r][3] + b4.w;
        if (RES) {
            const float4 rv = *(const float4*)&Rres[(size_t)m * N + n0 + tx * 4];
            v.x += rv.x; v.y += rv.y; v.z += rv.z; v.w += rv.w;
        }
        if (ACT == 1) {
            v.x = fmaxf(v.x, 0.f); v.y = fmaxf(v.y, 0.f);
            v.z = fmaxf(v.z, 0.f); v.w = fmaxf(v.w, 0.f);
        }
        *(float4*)&C[(size_t)m * N + n0 + tx * 4] = v;
    }
}

template<bool RES, int ACT>
__global__ __launch_bounds__(256)
void gemm_nt(const float* __restrict__ A, const float* __restrict__ B,
             const float* __restrict__ bias, const float* __restrict__ Rres,
             float* __restrict__ C, int K, int N) {
    gemm_tile<RES, ACT>(A, B, bias, Rres, C, K, N);
}

__global__ __launch_bounds__(256)
void gemm_qkv(const float* __restrict__ A, QKVArgs args, int K, int N) {
    const int z = blockIdx.z;
    gemm_tile<false, 0>(A, args.B[z], args.bias[z], nullptr, args.C[z], K, N);
}

// ---- attention: one 64-lane wave per (query q, head h) ----
__global__ __launch_bounds__(64)
void attn_kernel(const float* __restrict__ Q, const float* __restrict__ Km,
                 const float* __restrict__ V, float* __restrict__ O) {
    const int h = blockIdx.y;
    const int q = blockIdx.x;        // 0..256
    const int lane = threadIdx.x;    // 0..63
    __shared__ __align__(16) float qv[DH];
    __shared__ float pw[S];
    qv[lane] = Q[(size_t)q * D + h * DH + lane];
    __syncthreads();
    const float4* q4 = (const float4*)qv;
    float s[5];
    float mx = -1e30f;
    #pragma unroll
    for (int j = 0; j < 5; ++j) {
        const int kk = lane + j * 64;
        float dot = -1e30f;
        if (kk < S) {
            const float4* k4 = (const float4*)&Km[(size_t)kk * D + h * DH];
            float a0 = 0.f;
            #pragma unroll
            for (int d4 = 0; d4 < DH / 4; ++d4) {
                const float4 a = q4[d4];
                const float4 b = k4[d4];
                a0 = fmaf(a.x, b.x, a0); a0 = fmaf(a.y, b.y, a0);
                a0 = fmaf(a.z, b.z, a0); a0 = fmaf(a.w, b.w, a0);
            }
            dot = a0 * 0.125f;   // 1/sqrt(64)
        }
        s[j] = dot;
        mx = fmaxf(mx, dot);
    }
    #pragma unroll
    for (int off = 32; off; off >>= 1) mx = fmaxf(mx, __shfl_xor(mx, off, 64));
    float sum = 0.f;
    #pragma unroll
    for (int j = 0; j < 5; ++j) {
        const int kk = lane + j * 64;
        const float e = (kk < S) ? __expf(s[j] - mx) : 0.f;
        s[j] = e;
        sum += e;
    }
    #pragma unroll
    for (int off = 32; off; off >>= 1) sum += __shfl_xor(sum, off, 64);
    const float inv = 1.f / sum;
    #pragma unroll
    for (int j = 0; j < 5; ++j) {
        const int kk = lane + j * 64;
        if (kk < S) pw[kk] = s[j] * inv;
    }
    __syncthreads();
    float acc = 0.f;
    #pragma unroll 4
    for (int kk = 0; kk < S; ++kk)
        acc = fmaf(pw[kk], V[(size_t)kk * D + h * DH + lane], acc);
    O[(size_t)q * D + h * DH + lane] = acc;
}

// ---- embed observation: block per output d, 256-thread dot over OBS ----
__global__ __launch_bounds__(256)
void embed_obs_kernel(const float* __restrict__ obs, const float* __restrict__ Wc,
                      const float* __restrict__ bc, float* __restrict__ H) {
    const int d = blockIdx.x;
    const int t = threadIdx.x;
    const float4* w4 = (const float4*)&Wc[(size_t)d * OBS];
    const float4* o4 = (const float4*)obs;
    float acc = 0.f;
    #pragma unroll
    for (int i = t; i < OBS / 4; i += 256) {
        const float4 a = o4[i];
        const float4 b = w4[i];
        acc = fmaf(a.x, b.x, acc); acc = fmaf(a.y, b.y, acc);
        acc = fmaf(a.z, b.z, acc); acc = fmaf(a.w, b.w, acc);
    }
    __shared__ float red[256];
    red[t] = acc;
    __syncthreads();
    for (int off = 128; off; off >>= 1) {
        if (t < off) red[t] += red[t + off];
        __syncthreads();
    }
    if (t == 0) H[d] = red[0] + bc[d];
}

// ---- embed concepts + age; also zero-fill pad rows ----
__global__ __launch_bounds__(256)
void embed_concepts_kernel(const float* __restrict__ concepts, const float* __restrict__ Wce,
                           const float* __restrict__ bce, const float* __restrict__ Wa,
                           const float* __restrict__ ba, float* __restrict__ H) {
    const int row = blockIdx.x + 1;                 // 1..SP-1
    const int d = blockIdx.y * 256 + threadIdx.x;   // 0..1023
    if (row > NC) { H[(size_t)row * D + d] = 0.f; return; }
    const int i = row - 1;
    __shared__ __align__(16) float cs[CSZ];
    if (threadIdx.x < CSZ) cs[threadIdx.x] = concepts[(size_t)i * CSZ + threadIdx.x];
    __syncthreads();
    const float4* w4 = (const float4*)&Wce[(size_t)d * CSZ];
    const float4* c4 = (const float4*)cs;
    float acc = 0.f;
    #pragma unroll
    for (int c = 0; c < CSZ / 4; ++c) {
        const float4 a = c4[c];
        const float4 b = w4[c];
        acc = fmaf(a.x, b.x, acc); acc = fmaf(a.y, b.y, acc);
        acc = fmaf(a.z, b.z, acc); acc = fmaf(a.w, b.w, acc);
    }
    const float age = Wa[(size_t)d * AGE_V + i] +
                      ((float)i / 256.f) * Wa[(size_t)d * AGE_V + (AGE_V - 1)];
    H[(size_t)row * D + d] = acc + bce[d] + ba[d] + age;
}

// ---- layernorm over D=1024, one block per row ----
__global__ __launch_bounds__(256)
void ln_kernel(const float* __restrict__ X, const float* __restrict__ g,
               const float* __restrict__ b, float* __restrict__ Y) {
    const int r = blockIdx.x;
    const int t = threadIdx.x;
    const float* x = X + (size_t)r * D;
    float sm = 0.f, ss = 0.f;
    float v[4];
    #pragma unroll
    for (int j = 0; j < 4; ++j) {
        const float u = x[t + j * 256];
        v[j] = u;
        sm += u;
        ss = fmaf(u, u, ss);
    }
    __shared__ float r1[256], r2[256];
    r1[t] = sm; r2[t] = ss;
    __syncthreads();
    for (int off = 128; off; off >>= 1) {
        if (t < off) { r1[t] += r1[t + off]; r2[t] += r2[t + off]; }
        __syncthreads();
    }
    const float m  = r1[0] * (1.f / D);
    const float var = r2[0] * (1.f / D) - m * m;
    const float rs = rsqrtf(var + 1e-5f);
    #pragma unroll
    for (int j = 0; j < 4; ++j) {
        const int idx = t + j * 256;
        Y[(size_t)r * D + idx] = (v[j] - m) * rs * g[idx] + b[idx];
    }
}

// ---- output heads: 640 blocks, block j does one dot(h0, w_j) ----
__global__ __launch_bounds__(256)
void head_kernel(const float* __restrict__ H, const float* __restrict__ Wout,
                 const float* __restrict__ bout, const float* __restrict__ Wcon,
                 const float* __restrict__ bcon, float* __restrict__ out) {
    const int j = blockIdx.x;   // 0..639
    const int t = threadIdx.x;
    const float* w = (j < OUTN) ? &Wout[(size_t)j * D] : &Wcon[(size_t)(j - OUTN) * D];
    const float4* w4 = (const float4*)w;
    const float4* h4 = (const float4*)H;   // row 0
    const float4 a = h4[t];
    const float4 b = w4[t];
    float acc = a.x * b.x + a.y * b.y + a.z * b.z + a.w * b.w;
    __shared__ float red[256];
    red[t] = acc;
    __syncthreads();
    for (int off = 128; off; off >>= 1) {
        if (t < off) red[t] += red[t + off];
        __syncthreads();
    }
    if (t == 0) {
        const float v = red[0] + ((j < OUTN) ? bout[j] : bcon[j - OUTN]);
        out[j] = (j < OUTN) ? fmaxf(v, 0.f) : tanhf(v);
    }
}

extern "C" void kernel_launch(void* const* d_in, const int* in_sizes, int n_in,
                              void* d_out, int out_size, void* d_ws, size_t ws_size,
                              hipStream_t stream) {
    (void)in_sizes; (void)n_in; (void)out_size; (void)ws_size;
    const float* obs     = (const float*)d_in[0];
    const float* concepts= (const float*)d_in[1];
    const float* W_core  = (const float*)d_in[2];
    const float* b_core  = (const float*)d_in[3];
    const float* W_cemb  = (const float*)d_in[4];
    const float* b_cemb  = (const float*)d_in[5];
    const float* W_age   = (const float*)d_in[6];
    const float* b_age   = (const float*)d_in[7];
    const float* Wq      = (const float*)d_in[8];
    const float* bq      = (const float*)d_in[9];
    const float* Wk      = (const float*)d_in[10];
    const float* bk      = (const float*)d_in[11];
    const float* Wv      = (const float*)d_in[12];
    const float* bv      = (const float*)d_in[13];
    const float* Wo      = (const float*)d_in[14];
    const float* bo      = (const float*)d_in[15];
    const float* ln1g    = (const float*)d_in[16];
    const float* ln1b    = (const float*)d_in[17];
    const float* W1      = (const float*)d_in[18];
    const float* b1      = (const float*)d_in[19];
    const float* W2      = (const float*)d_in[20];
    const float* b2      = (const float*)d_in[21];
    const float* ln2g    = (const float*)d_in[22];
    const float* ln2b    = (const float*)d_in[23];
    const float* W_con   = (const float*)d_in[24];
    const float* b_con   = (const float*)d_in[25];
    const float* W_out   = (const float*)d_in[26];
    const float* b_out   = (const float*)d_in[27];
    float* outp = (float*)d_out;

    // workspace layout (floats). mid aliases q/k/v/att (exactly 4*SP*D = SP*HID).
    float* ws  = (float*)d_ws;
    float* h   = ws;                 // SP*D
    float* tmp = h   + (size_t)SP * D;
    float* qb  = tmp + (size_t)SP * D;
    float* kb  = qb  + (size_t)SP * D;
    float* vb  = kb  + (size_t)SP * D;
    float* att = vb  + (size_t)SP * D;
    float* mid = qb;                 // SP*HID, reuses q/k/v/att after attention

    embed_obs_kernel<<<dim3(D), 256, 0, stream>>>(obs, W_core, b_core, h);
    embed_concepts_kernel<<<dim3(SP - 1, D / 256), 256, 0, stream>>>(
        concepts, W_cemb, b_cemb, W_age, b_age, h);

    const dim3 gD(D / BN, SP / BM);
    const dim3 gH(HID / BN, SP / BM);
    for (int l = 0; l < NL; ++l) {
        QKVArgs qa;
        qa.B[0] = Wq + (size_t)l * D * D;  qa.bias[0] = bq + (size_t)l * D;  qa.C[0] = qb;
        qa.B[1] = Wk + (size_t)l * D * D;  qa.bias[1] = bk + (size_t)l * D;  qa.C[1] = kb;
        qa.B[2] = Wv + (size_t)l * D * D;  qa.bias[2] = bv + (size_t)l * D;  qa.C[2] = vb;
        gemm_qkv<<<dim3(D / BN, SP / BM, 3), 256, 0, stream>>>(h, qa, D, D);
        attn_kernel<<<dim3(S, HEADS), 64, 0, stream>>>(qb, kb, vb, att);
        gemm_nt<true, 0><<<gD, 256, 0, stream>>>(att, Wo + (size_t)l * D * D,
                                                 bo + (size_t)l * D, h, tmp, D, D);
        ln_kernel<<<dim3(S), 256, 0, stream>>>(tmp, ln1g + (size_t)l * D, ln1b + (size_t)l * D, h);
        gemm_nt<false, 1><<<gH, 256, 0, stream>>>(h, W1 + (size_t)l * HID * D,
                                                  b1 + (size_t)l * HID, nullptr, mid, D, HID);
        gemm_nt<true, 0><<<gD, 256, 0, stream>>>(mid, W2 + (size_t)l * D * HID,
                                                 b2 + (size_t)l * D, h, tmp, HID, D);
        ln_kernel<<<dim3(S), 256, 0, stream>>>(tmp, ln2g + (size_t)l * D, ln2b + (size_t)l * D, h);
    }
    head_kernel<<<dim3(OUTN + CSZ), 256, 0, stream>>>(h, W_out, b_out, W_con, b_con, outp);
}

// Round 2
// 1937.700 us; speedup vs baseline: 2.7301x; 2.7301x over previous
//
#include <hip/hip_runtime.h>
#include <hip/hip_bf16.h>
#include <cmath>

// ---- problem constants ----
constexpr int D     = 1024;
constexpr int HEADS = 16;
constexpr int DH    = 64;
constexpr int HID   = 4096;
constexpr int NL    = 12;
constexpr int NC    = 256;
constexpr int CSZ   = 128;
constexpr int AGE_V = 258;
constexpr int OBS   = 2048;
constexpr int OUTN  = 512;
constexpr int S     = 257;   // 1 + NC
constexpr int SP    = 288;   // padded rows: 3 * 96

typedef __attribute__((ext_vector_type(8))) short bf16x8v;
typedef __attribute__((ext_vector_type(4))) short short4v;
typedef __attribute__((ext_vector_type(4))) float f32x4;

__device__ __forceinline__ short bfc(float x) {
    __hip_bfloat16 h = __float2bfloat16(x);   // RNE
    return __builtin_bit_cast(short, h);
}
__device__ __forceinline__ void st_bf16x4(short* p, float4 v) {
    short4v s;
    s.x = bfc(v.x); s.y = bfc(v.y); s.z = bfc(v.z); s.w = bfc(v.w);
    *(short4v*)p = s;
}

// =====================================================================
// MFMA GEMM: C[M=288, N] = A[M,K] @ B[N,K]^T (+bias) (+relu | atomic)
// block tile 96x64, 4 waves in 2x2, per-wave 48x32 (3x2 mfma 16x16x32)
// fp32 global -> bf16 LDS conversion during staging; fp32 accumulate.
// EPI: 0 = store acc+bias, 1 = store relu(acc+bias), 2 = atomicAdd(acc)
// =====================================================================
constexpr int BM = 96, BN = 64, BK = 64, LDT = 72;  // LDT: +8 bf16 pad (16B, 2-way banks)

template<int EPI>
__device__ __forceinline__ void gemm_core(const float* __restrict__ A,
                                          const float* __restrict__ B,
                                          const float* __restrict__ bias,
                                          float* __restrict__ C,
                                          int K, int N, int kbeg, int klen) {
    __shared__ __align__(16) short As[BM * LDT];   // 13824 B
    __shared__ __align__(16) short Bs[BN * LDT];   //  9216 B
    const int t  = threadIdx.x;
    const int m0 = blockIdx.y * BM;
    const int n0 = blockIdx.x * BN;
    const int sr = t >> 4;          // 0..15
    const int sc = (t & 15) * 4;    // 0..60
    const float* Ab = A + (size_t)(m0 + sr) * K + kbeg + sc;
    const float* Bb = B + (size_t)(n0 + sr) * K + kbeg + sc;

    const int lane = t & 63, wave = t >> 6;
    const int wm = wave >> 1, wn = wave & 1;
    const int fr = lane & 15, quad = lane >> 4;
    const short* Abase = &As[(wm * 48 + fr) * LDT + quad * 8];
    const short* Bbase = &Bs[(wn * 32 + fr) * LDT + quad * 8];

    f32x4 acc[3][2] = {};

    for (int k0 = 0; k0 < klen; k0 += BK) {
        float4 av[6], bv[4];
        #pragma unroll
        for (int p = 0; p < 6; ++p)
            av[p] = *(const float4*)(Ab + (size_t)(p * 16) * K + k0);
        #pragma unroll
        for (int p = 0; p < 4; ++p)
            bv[p] = *(const float4*)(Bb + (size_t)(p * 16) * K + k0);
        __syncthreads();   // previous iter's LDS reads done
        #pragma unroll
        for (int p = 0; p < 6; ++p)
            st_bf16x4(&As[(p * 16 + sr) * LDT + sc], av[p]);
        #pragma unroll
        for (int p = 0; p < 4; ++p)
            st_bf16x4(&Bs[(p * 16 + sr) * LDT + sc], bv[p]);
        __syncthreads();
        #pragma unroll
        for (int kt = 0; kt < 2; ++kt) {
            bf16x8v af[3], bf[2];
            #pragma unroll
            for (int mt = 0; mt < 3; ++mt)
                af[mt] = *(const bf16x8v*)(Abase + mt * 16 * LDT + kt * 32);
            #pragma unroll
            for (int nt = 0; nt < 2; ++nt)
                bf[nt] = *(const bf16x8v*)(Bbase + nt * 16 * LDT + kt * 32);
            #pragma unroll
            for (int mt = 0; mt < 3; ++mt)
                #pragma unroll
                for (int nt = 0; nt < 2; ++nt)
                    acc[mt][nt] = __builtin_amdgcn_mfma_f32_16x16x32_bf16(
                        af[mt], bf[nt], acc[mt][nt], 0, 0, 0);
        }
    }

    #pragma unroll
    for (int mt = 0; mt < 3; ++mt) {
        #pragma unroll
        for (int nt = 0; nt < 2; ++nt) {
            const int m = m0 + wm * 48 + mt * 16 + quad * 4;
            const int n = n0 + wn * 32 + nt * 16 + fr;
            if (EPI == 2) {
                #pragma unroll
                for (int r = 0; r < 4; ++r)
                    atomicAdd(&C[(size_t)(m + r) * N + n], acc[mt][nt][r]);
            } else {
                const float bvv = bias[n];
                #pragma unroll
                for (int r = 0; r < 4; ++r) {
                    float v = acc[mt][nt][r] + bvv;
                    if (EPI == 1) v = fmaxf(v, 0.f);
                    C[(size_t)(m + r) * N + n] = v;
                }
            }
        }
    }
}

template<int EPI>
__global__ __launch_bounds__(256, 2)
void gemm_splitk(const float* __restrict__ A, const float* __restrict__ B,
                 const float* __restrict__ bias, float* __restrict__ C,
                 int K, int N, int klen) {
    gemm_core<EPI>(A, B, bias, C, K, N, blockIdx.z * klen, klen);
}

struct QKVArgs {
    const float* B[3];
    const float* bias[3];
    float* C[3];
};

__global__ __launch_bounds__(256, 2)
void gemm_qkv(const float* __restrict__ A, QKVArgs args, int K, int N) {
    const int z = blockIdx.z;
    gemm_core<0>(A, args.B[z], args.bias[z], args.C[z], K, N, 0, K);
}

// =====================================================================
// attention: block = (8 queries, head). 512 threads = 8 waves, wave = 1 query.
// K/V tiles (32 keys) staged in LDS, shared by all 8 waves.
// =====================================================================
constexpr int QB = 8, KT = 32, NT = 9;  // 9*32 = 288 >= 257

__global__ __launch_bounds__(512)
void attn_kernel(const float* __restrict__ Q, const float* __restrict__ Km,
                 const float* __restrict__ V, float* __restrict__ O) {
    __shared__ float Ks[KT * 66];     // stride 66: 2-way banks, float2-aligned
    __shared__ float Vs[KT * 64];
    __shared__ float pw[QB][NT * KT];
    const int h = blockIdx.y;
    const int t = threadIdx.x;
    const int wq = t >> 6, lane = t & 63;
    const int q = blockIdx.x * QB + wq;
    const bool qok = q < S;
    const int k32 = lane & 31, dh2 = lane >> 5;

    float qr[32];
    #pragma unroll
    for (int i = 0; i < 32; ++i)
        qr[i] = qok ? Q[(size_t)q * D + h * DH + dh2 * 32 + i] : 0.f;

    float s[NT];
    for (int tile = 0; tile < NT; ++tile) {
        const int kk0 = tile * KT;
        __syncthreads();
        #pragma unroll
        for (int p = 0; p < 2; ++p) {
            const int idx = t + p * 512;
            const int kr = idx >> 5, c2 = (idx & 31) * 2;
            const int kg = kk0 + kr;
            float2 v = make_float2(0.f, 0.f);
            if (kg < S) v = *(const float2*)&Km[(size_t)kg * D + h * DH + c2];
            *(float2*)&Ks[kr * 66 + c2] = v;
        }
        __syncthreads();
        float dot = 0.f;
        const float* kp = &Ks[k32 * 66 + dh2 * 32];
        #pragma unroll
        for (int i = 0; i < 32; ++i) dot = fmaf(qr[i], kp[i], dot);
        dot += __shfl_xor(dot, 32, 64);
        s[tile] = (kk0 + k32 < S) ? dot * 0.125f : -1e30f;
    }
    // softmax (scores duplicated across dh2 halves)
    float mx = -1e30f;
    #pragma unroll
    for (int j = 0; j < NT; ++j) mx = fmaxf(mx, s[j]);
    #pragma unroll
    for (int off = 32; off; off >>= 1) mx = fmaxf(mx, __shfl_xor(mx, off, 64));
    float sum = 0.f;
    #pragma unroll
    for (int j = 0; j < NT; ++j) {
        const float e = __expf(s[j] - mx);
        s[j] = e;
        sum += e;
    }
    #pragma unroll
    for (int off = 32; off; off >>= 1) sum += __shfl_xor(sum, off, 64);
    sum *= 0.5f;   // each key counted in both dh2 halves
    const float inv = 1.f / sum;
    if (qok && dh2 == 0) {
        #pragma unroll
        for (int j = 0; j < NT; ++j) pw[wq][j * KT + k32] = s[j] * inv;
    }
    // PV
    float acc = 0.f;
    for (int tile = 0; tile < NT; ++tile) {
        const int kk0 = tile * KT;
        __syncthreads();
        {
            const int kr = t >> 4, c4 = (t & 15) * 4;
            const int kg = kk0 + kr;
            float4 v = make_float4(0.f, 0.f, 0.f, 0.f);
            if (kg < S) v = *(const float4*)&V[(size_t)kg * D + h * DH + c4];
            *(float4*)&Vs[kr * 64 + c4] = v;
        }
        __syncthreads();
        if (qok) {
            const float* pwp = &pw[wq][kk0];
            #pragma unroll
            for (int k = 0; k < KT; ++k)
                acc = fmaf(pwp[k], Vs[k * 64 + lane], acc);
        }
    }
    if (qok) O[(size_t)q * D + h * DH + lane] = acc;
}

// ---- embed observation; also init tmpA = h + bo[0] ----
__global__ __launch_bounds__(256)
void embed_obs_kernel(const float* __restrict__ obs, const float* __restrict__ Wc,
                      const float* __restrict__ bc, const float* __restrict__ bo0,
                      float* __restrict__ H, float* __restrict__ T) {
    const int d = blockIdx.x;
    const int t = threadIdx.x;
    const float4* w4 = (const float4*)&Wc[(size_t)d * OBS];
    const float4* o4 = (const float4*)obs;
    float acc = 0.f;
    #pragma unroll
    for (int i = t; i < OBS / 4; i += 256) {
        const float4 a = o4[i];
        const float4 b = w4[i];
        acc = fmaf(a.x, b.x, acc); acc = fmaf(a.y, b.y, acc);
        acc = fmaf(a.z, b.z, acc); acc = fmaf(a.w, b.w, acc);
    }
    __shared__ float red[256];
    red[t] = acc;
    __syncthreads();
    for (int off = 128; off; off >>= 1) {
        if (t < off) red[t] += red[t + off];
        __syncthreads();
    }
    if (t == 0) {
        const float v = red[0] + bc[d];
        H[d] = v;
        T[d] = v + bo0[d];
    }
}

// ---- embed concepts + age; zero-fill pad rows; init tmpA = h + bo[0] ----
__global__ __launch_bounds__(256)
void embed_concepts_kernel(const float* __restrict__ concepts, const float* __restrict__ Wce,
                           const float* __restrict__ bce, const float* __restrict__ Wa,
                           const float* __restrict__ ba, const float* __restrict__ bo0,
                           float* __restrict__ H, float* __restrict__ T) {
    const int row = blockIdx.x + 1;                 // 1..SP-1
    const int d = blockIdx.y * 256 + threadIdx.x;   // 0..1023
    if (row > NC) {
        H[(size_t)row * D + d] = 0.f;
        T[(size_t)row * D + d] = bo0[d];
        return;
    }
    const int i = row - 1;
    __shared__ __align__(16) float cs[CSZ];
    if (threadIdx.x < CSZ) cs[threadIdx.x] = concepts[(size_t)i * CSZ + threadIdx.x];
    __syncthreads();
    const float4* w4 = (const float4*)&Wce[(size_t)d * CSZ];
    const float4* c4 = (const float4*)cs;
    float acc = 0.f;
    #pragma unroll
    for (int c = 0; c < CSZ / 4; ++c) {
        const float4 a = c4[c];
        const float4 b = w4[c];
        acc = fmaf(a.x, b.x, acc); acc = fmaf(a.y, b.y, acc);
        acc = fmaf(a.z, b.z, acc); acc = fmaf(a.w, b.w, acc);
    }
    const float age = Wa[(size_t)d * AGE_V + i] +
                      ((float)i / 256.f) * Wa[(size_t)d * AGE_V + (AGE_V - 1)];
    const float v = acc + bce[d] + ba[d] + age;
    H[(size_t)row * D + d] = v;
    T[(size_t)row * D + d] = v + bo0[d];
}

// ---- layernorm; optional fused init of next accumulation buffer ----
__global__ __launch_bounds__(256)
void ln_kernel(const float* __restrict__ X, const float* __restrict__ g,
               const float* __restrict__ b, float* __restrict__ Y,
               float* __restrict__ Tinit, const float* __restrict__ nbias) {
    const int r = blockIdx.x;
    const int t = threadIdx.x;
    const float* x = X + (size_t)r * D;
    float sm = 0.f, ss = 0.f;
    float v[4];
    #pragma unroll
    for (int j = 0; j < 4; ++j) {
        const float u = x[t + j * 256];
        v[j] = u;
        sm += u;
        ss = fmaf(u, u, ss);
    }
    __shared__ float r1[256], r2[256];
    r1[t] = sm; r2[t] = ss;
    __syncthreads();
    for (int off = 128; off; off >>= 1) {
        if (t < off) { r1[t] += r1[t + off]; r2[t] += r2[t + off]; }
        __syncthreads();
    }
    const float m   = r1[0] * (1.f / D);
    const float var = r2[0] * (1.f / D) - m * m;
    const float rs  = rsqrtf(var + 1e-5f);
    #pragma unroll
    for (int j = 0; j < 4; ++j) {
        const int idx = t + j * 256;
        const float y = (v[j] - m) * rs * g[idx] + b[idx];
        Y[(size_t)r * D + idx] = y;
        if (Tinit) Tinit[(size_t)r * D + idx] = y + nbias[idx];
    }
}

// ---- output heads ----
__global__ __launch_bounds__(256)
void head_kernel(const float* __restrict__ H, const float* __restrict__ Wout,
                 const float* __restrict__ bout, const float* __restrict__ Wcon,
                 const float* __restrict__ bcon, float* __restrict__ out) {
    const int j = blockIdx.x;   // 0..639
    const int t = threadIdx.x;
    const float* w = (j < OUTN) ? &Wout[(size_t)j * D] : &Wcon[(size_t)(j - OUTN) * D];
    const float4* w4 = (const float4*)w;
    const float4* h4 = (const float4*)H;   // row 0
    const float4 a = h4[t];
    const float4 b = w4[t];
    float acc = a.x * b.x + a.y * b.y + a.z * b.z + a.w * b.w;
    __shared__ float red[256];
    red[t] = acc;
    __syncthreads();
    for (int off = 128; off; off >>= 1) {
        if (t < off) red[t] += red[t + off];
        __syncthreads();
    }
    if (t == 0) {
        const float v = red[0] + ((j < OUTN) ? bout[j] : bcon[j - OUTN]);
        out[j] = (j < OUTN) ? fmaxf(v, 0.f) : tanhf(v);
    }
}

extern "C" void kernel_launch(void* const* d_in, const int* in_sizes, int n_in,
                              void* d_out, int out_size, void* d_ws, size_t ws_size,
                              hipStream_t stream) {
    (void)in_sizes; (void)n_in; (void)out_size; (void)ws_size;
    const float* obs     = (const float*)d_in[0];
    const float* concepts= (const float*)d_in[1];
    const float* W_core  = (const float*)d_in[2];
    const float* b_core  = (const float*)d_in[3];
    const float* W_cemb  = (const float*)d_in[4];
    const float* b_cemb  = (const float*)d_in[5];
    const float* W_age   = (const float*)d_in[6];
    const float* b_age   = (const float*)d_in[7];
    const float* Wq      = (const float*)d_in[8];
    const float* bq      = (const float*)d_in[9];
    const float* Wk      = (const float*)d_in[10];
    const float* bk      = (const float*)d_in[11];
    const float* Wv      = (const float*)d_in[12];
    const float* bv      = (const float*)d_in[13];
    const float* Wo      = (const float*)d_in[14];
    const float* bo      = (const float*)d_in[15];
    const float* ln1g    = (const float*)d_in[16];
    const float* ln1b    = (const float*)d_in[17];
    const float* W1      = (const float*)d_in[18];
    const float* b1      = (const float*)d_in[19];
    const float* W2      = (const float*)d_in[20];
    const float* b2      = (const float*)d_in[21];
    const float* ln2g    = (const float*)d_in[22];
    const float* ln2b    = (const float*)d_in[23];
    const float* W_con   = (const float*)d_in[24];
    const float* b_con   = (const float*)d_in[25];
    const float* W_out   = (const float*)d_in[26];
    const float* b_out   = (const float*)d_in[27];
    float* outp = (float*)d_out;

    // workspace: h, tmpA, tmpB, qb, kb, vb, att (7 x SP*D floats); mid = qb..att
    float* ws   = (float*)d_ws;
    float* h    = ws;
    float* tmpA = h    + (size_t)SP * D;
    float* tmpB = tmpA + (size_t)SP * D;
    float* qb   = tmpB + (size_t)SP * D;
    float* kb   = qb   + (size_t)SP * D;
    float* vb   = kb   + (size_t)SP * D;
    float* att  = vb   + (size_t)SP * D;
    float* mid  = qb;   // SP*HID = 4 slabs (qb,kb,vb,att), dead by W1 time

    embed_obs_kernel<<<dim3(D), 256, 0, stream>>>(obs, W_core, b_core, bo, h, tmpA);
    embed_concepts_kernel<<<dim3(SP - 1, D / 256), 256, 0, stream>>>(
        concepts, W_cemb, b_cemb, W_age, b_age, bo, h, tmpA);

    for (int l = 0; l < NL; ++l) {
        QKVArgs qa;
        qa.B[0] = Wq + (size_t)l * D * D;  qa.bias[0] = bq + (size_t)l * D;  qa.C[0] = qb;
        qa.B[1] = Wk + (size_t)l * D * D;  qa.bias[1] = bk + (size_t)l * D;  qa.C[1] = kb;
        qa.B[2] = Wv + (size_t)l * D * D;  qa.bias[2] = bv + (size_t)l * D;  qa.C[2] = vb;
        gemm_qkv<<<dim3(D / BN, SP / BM, 3), 256, 0, stream>>>(h, qa, D, D);
        attn_kernel<<<dim3((S + QB - 1) / QB, HEADS), 512, 0, stream>>>(qb, kb, vb, att);
        // tmpA = h + bo (pre-initialized); O-proj accumulates atomically, split-K x4
        gemm_splitk<2><<<dim3(D / BN, SP / BM, 4), 256, 0, stream>>>(
            att, Wo + (size_t)l * D * D, nullptr, tmpA, D, D, 256);
        // ln1: h = LN(tmpA); tmpB = h + b2[l]
        ln_kernel<<<dim3(S), 256, 0, stream>>>(tmpA, ln1g + (size_t)l * D,
                                               ln1b + (size_t)l * D, h,
                                               tmpB, b2 + (size_t)l * D);
        // W1 + relu, no split
        gemm_splitk<1><<<dim3(HID / BN, SP / BM, 1), 256, 0, stream>>>(
            h, W1 + (size_t)l * HID * D, b1 + (size_t)l * HID, mid, D, HID, D);
        // W2 accumulates into tmpB (= h + b2), split-K x8
        gemm_splitk<2><<<dim3(D / BN, SP / BM, 8), 256, 0, stream>>>(
            mid, W2 + (size_t)l * D * HID, nullptr, tmpB, HID, D, 512);
        // ln2: h = LN(tmpB); tmpA = h + bo[l+1] (next layer's O accumulation base)
        float* ti = (l + 1 < NL) ? tmpA : nullptr;
        const float* nb = (l + 1 < NL) ? (bo + (size_t)(l + 1) * D) : nullptr;
        ln_kernel<<<dim3(S), 256, 0, stream>>>(tmpB, ln2g + (size_t)l * D,
                                               ln2b + (size_t)l * D, h, ti, nb);
    }
    head_kernel<<<dim3(OUTN + CSZ), 256, 0, stream>>>(h, W_out, b_out, W_con, b_con, outp);
}